// Round 1
// baseline (193.008 us; speedup 1.0000x reference)
//
#include <hip/hip_runtime.h>
#include <math.h>

// CTC-CRF NLL: mean_b( logZ_den(b) - logZ_num(b) ), B=16,T=2048,S=8,L=256.
//
// R12 = R11 + role fusion. R11 ran 48 blocks x 128thr (3 roles x 16 samples)
// -> <=1 wave/SIMD device-wide; active-CU VALUBusy ~13% => waves ~87%
// latency-stalled with nothing co-resident to fill the bubbles. R12 fuses:
//   8 blocks x 512thr, each block = 2 samples x 4 role-waves
//   (num-fwd, num-bwd, den-fwd, den-bwd) = 8 waves = 2 waves/SIMD, so a
//   num wave is paired with a den wave on each SIMD and their stalls
//   interleave.
// Also: emissions staged ONCE per sample (was 3x device-wide); den reads
// the padded transposed streams directly (row-interleaved copy deleted);
// den inner loop double-buffers its 4-step chunk loads (was exposed ~120cy
// per chunk). All per-role math is op-for-op identical to R11.
// LDS = 2 samples x 4 streams x (T+2) float2 = 131.2KB -> raise dynamic-LDS
// cap via hipFuncSetAttribute (gfx950 workgroup LDS max = 160KB).

#define LOG2E 1.4426950408889634f
#define LN2   0.69314718055994531f
#define CTL_WSHL1  0x130            // DPP wave_shl:1 (lane63 -> 0)
#define CTL_WSHR1  0x138            // DPP wave_shr:1 (lane0  -> 0)
#define CTL_ROR(r) (0x120 + (r))    // DPP row_ror:r

#define AST(p, v) __hip_atomic_store((p), (v), __ATOMIC_RELAXED, __HIP_MEMORY_SCOPE_AGENT)
#define ALD(p)    __hip_atomic_load((p), __ATOMIC_RELAXED, __HIP_MEMORY_SCOPE_AGENT)

template <int CTRL>
__device__ __forceinline__ float fdpp(float x) {
    return __int_as_float(__builtin_amdgcn_update_dpp(
        0, __float_as_int(x), CTRL, 0xF, 0xF, true));
}
template <int CTRL>
__device__ __forceinline__ int idpp(int x) {
    return __builtin_amdgcn_update_dpp(0, x, CTRL, 0xF, 0xF, true);
}

__device__ __forceinline__ void pin() {      // scheduler fence (MIR-level)
#if __has_builtin(__builtin_amdgcn_sched_barrier)
    __builtin_amdgcn_sched_barrier(0);
#else
    asm volatile("" ::: "memory");
#endif
}

__device__ __forceinline__ float fexp2(float x) {
#if __has_builtin(__builtin_amdgcn_exp2f)
    return __builtin_amdgcn_exp2f(x);
#else
    return exp2f(x);
#endif
}
__device__ __forceinline__ float flog2(float x) {
#if __has_builtin(__builtin_amdgcn_logf)
    return __builtin_amdgcn_logf(x);
#else
    return __log2f(x);
#endif
}
__device__ __forceinline__ float lse2(float a, float b) {   // log2(2^a+2^b)
    float m = fmaxf(a, b);
    float d = fminf(a, b) - m;
    return m + flog2(1.0f + fexp2(d));
}

struct NumC { float tee[4], txe[4], tex[4], txx[4]; };

// ---------------- forward numerator (proven) ----------------
__device__ __forceinline__ void numf_step(const float2* p, float* E, float* X,
                                          float teeF, float txeF, const NumC& c) {
    float nbE = fdpp<CTL_WSHR1>(E[3]);
    float nbX = fdpp<CTL_WSHR1>(X[3]);
    float nE0 = p[0].x * fmaf(nbE,  teeF,     nbX  * txeF);
    float nE1 = p[1].x * fmaf(E[0], c.tee[1], X[0] * c.txe[1]);
    float nE2 = p[2].x * fmaf(E[1], c.tee[2], X[1] * c.txe[2]);
    float nE3 = p[3].x * fmaf(E[2], c.tee[3], X[2] * c.txe[3]);
    float nX0 = p[0].y * fmaf(E[0], c.tex[0], X[0] * c.txx[0]);
    float nX1 = p[1].y * fmaf(E[1], c.tex[1], X[1] * c.txx[1]);
    float nX2 = p[2].y * fmaf(E[2], c.tex[2], X[2] * c.txx[2]);
    float nX3 = p[3].y * fmaf(E[3], c.tex[3], X[3] * c.txx[3]);
    E[0] = nE0; E[1] = nE1; E[2] = nE2; E[3] = nE3;
    X[0] = nX0; X[1] = nX1; X[2] = nX2; X[3] = nX3;
}

__device__ __forceinline__ void numf_boundary(float* E, float* X, int& s,
                                              float& teeF, float& txeF,
                                              int lane, const NumC& c) {
    float m = fmaxf(fmaxf(fmaxf(E[0], E[1]), fmaxf(E[2], E[3])),
                    fmaxf(fmaxf(X[0], X[1]), fmaxf(X[2], X[3])));
    const bool live = (m > 0.0f);
    const int ex = live ? ((int)(__float_as_uint(m) >> 23) - 126) : 0;
    s += ex;
    const int bs = idpp<CTL_WSHR1>(s);
    if (!live) s = bs;
    int d = (lane == 0) ? 0 : (bs - s);
    const int extra = (d > 30) ? d : 0;
    s += extra; d -= extra;
    const float fsc = ldexpf(1.0f, -(ex + extra));
#pragma unroll
    for (int k = 0; k < 4; ++k) { E[k] *= fsc; X[k] *= fsc; }
    const float fs0 = (lane == 0) ? 0.0f : ldexpf(1.0f, d);
    teeF = c.tee[0] * fs0;
    txeF = c.txe[0] * fs0;
}

// ---------------- backward numerator (proven) ----------------
__device__ __forceinline__ void numb_step(const float2* p, float* bE, float* bX,
                                          const float* tex, const float* txx,
                                          const float* teeN, const float* txeN,
                                          float teeN3F, float txeN3F) {
    float mm0 = p[0].x * bE[0];
    float mm1 = p[1].x * bE[1];
    float mm2 = p[2].x * bE[2];
    float mm3 = p[3].x * bE[3];
    float m10 = p[0].y * bX[0];
    float m11 = p[1].y * bX[1];
    float m12 = p[2].y * bX[2];
    float m13 = p[3].y * bX[3];
    float mup = fdpp<CTL_WSHL1>(mm0);
    float nE0 = fmaf(tex[0], m10, teeN[0] * mm1);
    float nE1 = fmaf(tex[1], m11, teeN[1] * mm2);
    float nE2 = fmaf(tex[2], m12, teeN[2] * mm3);
    float nE3 = fmaf(tex[3], m13, teeN3F   * mup);
    float nX0 = fmaf(txx[0], m10, txeN[0] * mm1);
    float nX1 = fmaf(txx[1], m11, txeN[1] * mm2);
    float nX2 = fmaf(txx[2], m12, txeN[2] * mm3);
    float nX3 = fmaf(txx[3], m13, txeN3F   * mup);
    bE[0] = nE0; bE[1] = nE1; bE[2] = nE2; bE[3] = nE3;
    bX[0] = nX0; bX[1] = nX1; bX[2] = nX2; bX[3] = nX3;
}

__device__ __forceinline__ void numb_boundary(float* bE, float* bX, int& s,
                                              float& teeN3F, float& txeN3F,
                                              int lane, float teeN3, float txeN3) {
    float m = fmaxf(fmaxf(fmaxf(bE[0], bE[1]), fmaxf(bE[2], bE[3])),
                    fmaxf(fmaxf(bX[0], bX[1]), fmaxf(bX[2], bX[3])));
    const bool live = (m > 0.0f);
    const int ex = live ? ((int)(__float_as_uint(m) >> 23) - 126) : 0;
    s += ex;
    const int bs = idpp<CTL_WSHL1>(s);
    if (!live) s = bs;
    int d = (lane == 63) ? 0 : (bs - s);
    const int extra = (d > 30) ? d : 0;
    s += extra; d -= extra;
    const float fsc = ldexpf(1.0f, -(ex + extra));
#pragma unroll
    for (int k = 0; k < 4; ++k) { bE[k] *= fsc; bX[k] *= fsc; }
    const float fs = (lane == 63) ? 0.0f : ldexpf(1.0f, d);
    teeN3F = teeN3 * fs;
    txeN3F = txeN3 * fs;
}

// ---------------- 4-step executors over float4 buffers ----------------
__device__ __forceinline__ void steps4_fwd(const float4 buf[4][2], float* E, float* X,
                                           float teeF, float txeF, const NumC& c) {
#pragma unroll
    for (int q = 0; q < 4; ++q) {
        float2 p[4];
#pragma unroll
        for (int k = 0; k < 4; ++k) {
            const float4 v = buf[k][q >> 1];
            p[k] = (q & 1) ? make_float2(v.z, v.w) : make_float2(v.x, v.y);
        }
        numf_step(p, E, X, teeF, txeF, c);
    }
}
__device__ __forceinline__ void steps4_bwd(const float4 buf[4][2], float* bE, float* bX,
                                           const float* tex, const float* txx,
                                           const float* teeN, const float* txeN,
                                           float teeN3F, float txeN3F) {
#pragma unroll
    for (int q = 0; q < 4; ++q) {            // t, t-1, t-2, t-3 (t odd)
        const int h = 1 - (q >> 1);
        float2 p[4];
#pragma unroll
        for (int k = 0; k < 4; ++k) {
            const float4 v = buf[k][h];
            p[k] = (q & 1) ? make_float2(v.x, v.y) : make_float2(v.z, v.w);
        }
        numb_step(p, bE, bX, tex, txx, teeN, txeN, teeN3F, txeN3F);
    }
}

// ---------------- denominator steps (proven) ----------------
__device__ __forceinline__ float denf_step(float al, float emt, const float* Tr) {
    float v1 = fdpp<CTL_ROR(1)>(al);
    float v2 = fdpp<CTL_ROR(2)>(al);
    float v3 = fdpp<CTL_ROR(3)>(al);
    float v4 = fdpp<CTL_ROR(4)>(al);
    float v5 = fdpp<CTL_ROR(5)>(al);
    float v6 = fdpp<CTL_ROR(6)>(al);
    float v7 = fdpp<CTL_ROR(7)>(al);
    float q0 = fmaf(v1, Tr[1], al * Tr[0]);
    float q1 = fmaf(v3, Tr[3], v2 * Tr[2]);
    float q2 = fmaf(v5, Tr[5], v4 * Tr[4]);
    float q3 = fmaf(v7, Tr[7], v6 * Tr[6]);
    return ((q0 + q1) + (q2 + q3)) * emt;
}
__device__ __forceinline__ float denb_step(float al, float emt, const float* TrB) {
    float g  = al * emt;
    float v1 = fdpp<CTL_ROR(7)>(g);
    float v2 = fdpp<CTL_ROR(6)>(g);
    float v3 = fdpp<CTL_ROR(5)>(g);
    float v4 = fdpp<CTL_ROR(4)>(g);
    float v5 = fdpp<CTL_ROR(3)>(g);
    float v6 = fdpp<CTL_ROR(2)>(g);
    float v7 = fdpp<CTL_ROR(1)>(g);
    float q0 = fmaf(v1, TrB[1], g * TrB[0]);
    float q1 = fmaf(v3, TrB[3], v2 * TrB[2]);
    float q2 = fmaf(v5, TrB[5], v4 * TrB[4]);
    float q3 = fmaf(v7, TrB[7], v6 * TrB[6]);
    return (q0 + q1) + (q2 + q3);
}
__device__ __forceinline__ int den_renorm(float& al) {
    float mm = fmaxf(al, fdpp<CTL_ROR(4)>(al));
    mm = fmaxf(mm, fdpp<CTL_ROR(2)>(mm));
    mm = fmaxf(mm, fdpp<CTL_ROR(1)>(mm));
    const int ex = (int)(__float_as_uint(mm) >> 23) - 126;
    al = ldexpf(al, -ex);
    return ex;
}

extern "C" __global__ void __launch_bounds__(512)
crf_fused(const float* __restrict__ em, const float* __restrict__ trans,
          const float* __restrict__ bos, const float* __restrict__ eos,
          const int* __restrict__ lengths, const int* __restrict__ targets,
          const int* __restrict__ tlens,
          float* __restrict__ ws, float* __restrict__ out,
          int B, int T, int S, int L)
{
    extern __shared__ float sm[];
    const int bid  = blockIdx.x;
    const int tid  = threadIdx.x;
    const int lane = tid & 63;
    const int wv   = tid >> 6;
    const int half = S >> 1;                 // = 4
    const int role = wv >> 1;                // 0 num-fwd, 1 num-bwd, 2 den-fwd, 3 den-bwd
    const int smp  = wv & 1;                 // sample within block
    const int b    = 2 * bid + smp;
    const int len  = lengths[(b < B) ? b : 0];
    const int tm   = (len - 1) >> 1;
    const int P2   = T + 2;                  // padded float2 pitch per stream
    const int Th2  = P2 >> 1;                // float4 pitch per stream
    const int SPF  = 4 * P2;                 // float2 per sample region

    float* NF  = ws + 16 + (size_t)b * 576;
    float* NB  = ws + 16 + (size_t)B * 576 + (size_t)b * 576;
    float* DEN = ws + 16 + (size_t)(2 * B) * 576;
    int* ticket = (int*)ws;

    // ---------------- staging: both samples, transposed padded streams ----
    {
        float2* s2w = (float2*)sm;
        const int nrows = (2 * bid + 2 <= B) ? 2 * T : T;
        for (int i = tid; i < nrows; i += 512) {
            const int si = (i >= T) ? 1 : 0;
            const int t  = i - si * T;
            const float4* gr =
                (const float4*)(em + ((size_t)(2 * bid + si) * T + t) * S);
            float4 a = gr[0], c4 = gr[1];
            float2* s2s = s2w + si * SPF;
            s2s[0 * P2 + t] = make_float2(fexp2(a.x * LOG2E), fexp2(c4.x * LOG2E));
            s2s[1 * P2 + t] = make_float2(fexp2(a.y * LOG2E), fexp2(c4.y * LOG2E));
            s2s[2 * P2 + t] = make_float2(fexp2(a.z * LOG2E), fexp2(c4.z * LOG2E));
            s2s[3 * P2 + t] = make_float2(fexp2(a.w * LOG2E), fexp2(c4.w * LOG2E));
        }
    }
    __syncthreads();

    const float2* s2 = (const float2*)sm + smp * SPF;
    const float4* s4 = (const float4*)sm + smp * (SPF >> 1);
    float* scr = sm + 4 * SPF + smp * 32;    // [0..7] denF, [8..15] denB,
                                             // ints [16..23] denFs, [24..31] denBs

    if (role == 0 && b < B) {
        // =================== NUMERATOR FORWARD: t = 1..tm ===================
        const int u0 = lane * 4;
        int e[4], ep[4];
        const int base = b * L;
#pragma unroll
        for (int k = 0; k < 4; ++k) {
            int u = u0 + k;
            e[k] = targets[base + ((u < L) ? u : (L - 1))];
        }
        ep[0] = (u0 > 0) ? targets[base + u0 - 1] : e[0];
        ep[1] = e[0]; ep[2] = e[1]; ep[3] = e[2];
        NumC c;
#pragma unroll
        for (int k = 0; k < 4; ++k) {
            c.tee[k] = fexp2(trans[ep[k] * S + e[k]] * LOG2E);
            c.txe[k] = fexp2(trans[(ep[k] + half) * S + e[k]] * LOG2E);
            c.tex[k] = fexp2(trans[e[k] * S + e[k] + half] * LOG2E);
            c.txx[k] = fexp2(trans[(e[k] + half) * S + e[k] + half] * LOG2E);
        }
        float E[4] = {0.f,0.f,0.f,0.f}, X[4] = {0.f,0.f,0.f,0.f};
        int s = 0;
        if (lane == 0) E[0] = fexp2(bos[e[0]] * LOG2E) * s2[e[0] * P2].x;
        float teeF = (lane == 0) ? 0.0f : c.tee[0];
        float txeF = (lane == 0) ? 0.0f : c.txe[0];

        int t0 = 1;
        while (t0 <= tm && (t0 & 1)) {       // align to even t0
            float2 p[4];
#pragma unroll
            for (int k = 0; k < 4; ++k) p[k] = s2[e[k] * P2 + t0];
            numf_step(p, E, X, teeF, txeF, c);
            ++t0;
        }
        if (t0 + 7 <= tm) {
            float4 A[4][2], Bf[4][2];
#pragma unroll
            for (int k = 0; k < 4; ++k) {
                A[k][0] = s4[e[k] * Th2 + (t0 >> 1)];
                A[k][1] = s4[e[k] * Th2 + ((t0 + 2) >> 1)];
            }
            pin();
            while (t0 + 7 <= tm) {
#pragma unroll
                for (int k = 0; k < 4; ++k) {
                    Bf[k][0] = s4[e[k] * Th2 + ((t0 + 4) >> 1)];
                    Bf[k][1] = s4[e[k] * Th2 + ((t0 + 6) >> 1)];
                }
                pin();
                steps4_fwd(A, E, X, teeF, txeF, c);
#pragma unroll
                for (int k = 0; k < 4; ++k) {      // t0+10 <= tm+3 < T: valid
                    A[k][0] = s4[e[k] * Th2 + ((t0 + 8) >> 1)];
                    A[k][1] = s4[e[k] * Th2 + ((t0 + 10) >> 1)];
                }
                pin();
                steps4_fwd(Bf, E, X, teeF, txeF, c);
                numf_boundary(E, X, s, teeF, txeF, lane, c);
                t0 += 8;
            }
        }
        while (t0 <= tm) {                   // tail
            float2 p[4];
#pragma unroll
            for (int k = 0; k < 4; ++k) p[k] = s2[e[k] * P2 + t0];
            numf_step(p, E, X, teeF, txeF, c);
            ++t0;
        }
#pragma unroll
        for (int k = 0; k < 4; ++k) {
            AST(&NF[lane * 8 + k],     E[k]);
            AST(&NF[lane * 8 + 4 + k], X[k]);
        }
        AST(&NF[512 + lane], __int_as_float(s));
    } else if (role == 1 && b < B) {
        // =================== NUMERATOR BACKWARD: t = len-1..tm+1 ===========
        const int u0 = lane * 4;
        int e[5];
        const int base = b * L;
#pragma unroll
        for (int k = 0; k < 5; ++k) {
            int u = u0 + k;
            e[k] = targets[base + ((u < L) ? u : (L - 1))];
        }
        float tex[4], txx[4], teeN[4], txeN[4];
#pragma unroll
        for (int k = 0; k < 4; ++k) {
            tex[k]  = fexp2(trans[e[k] * S + e[k] + half] * LOG2E);
            txx[k]  = fexp2(trans[(e[k] + half) * S + e[k] + half] * LOG2E);
            teeN[k] = fexp2(trans[e[k] * S + e[k + 1]] * LOG2E);
            txeN[k] = fexp2(trans[(e[k] + half) * S + e[k + 1]] * LOG2E);
        }
        if (lane == 63) { teeN[3] = 0.0f; txeN[3] = 0.0f; }
        float bE[4] = {0.f,0.f,0.f,0.f}, bX[4] = {0.f,0.f,0.f,0.f};
        const int uf = tlens[b] - 1;
        if (lane == (uf >> 2)) {
            const int kf = uf & 3;
            bE[kf] = fexp2(eos[e[kf]] * LOG2E);
            bX[kf] = fexp2(eos[e[kf] + half] * LOG2E);
        }
        int s = 0;
        float teeN3F = teeN[3], txeN3F = txeN[3];

        int t1 = len - 1;
        const int tlo = tm + 1;
        while (t1 >= tlo && !(t1 & 1)) {     // align to odd t1
            float2 p[4];
#pragma unroll
            for (int k = 0; k < 4; ++k) p[k] = s2[e[k] * P2 + t1];
            numb_step(p, bE, bX, tex, txx, teeN, txeN, teeN3F, txeN3F);
            --t1;
        }
        if (t1 - 7 >= tlo) {
            float4 A[4][2], Bf[4][2];
#pragma unroll
            for (int k = 0; k < 4; ++k) {
                A[k][0] = s4[e[k] * Th2 + ((t1 - 3) >> 1)];
                A[k][1] = s4[e[k] * Th2 + ((t1 - 1) >> 1)];
            }
            pin();
            while (t1 - 7 >= tlo) {
#pragma unroll
                for (int k = 0; k < 4; ++k) {
                    Bf[k][0] = s4[e[k] * Th2 + ((t1 - 7) >> 1)];
                    Bf[k][1] = s4[e[k] * Th2 + ((t1 - 5) >> 1)];
                }
                pin();
                steps4_bwd(A, bE, bX, tex, txx, teeN, txeN, teeN3F, txeN3F);
                const int ta = (t1 - 11 > 0) ? (t1 - 11) : 0;   // even; >=0
#pragma unroll
                for (int k = 0; k < 4; ++k) {
                    A[k][0] = s4[e[k] * Th2 + (ta >> 1)];
                    A[k][1] = s4[e[k] * Th2 + ((ta + 2) >> 1)];
                }
                pin();
                steps4_bwd(Bf, bE, bX, tex, txx, teeN, txeN, teeN3F, txeN3F);
                numb_boundary(bE, bX, s, teeN3F, txeN3F, lane, teeN[3], txeN[3]);
                t1 -= 8;
            }
        }
        while (t1 >= tlo) {                  // tail
            float2 p[4];
#pragma unroll
            for (int k = 0; k < 4; ++k) p[k] = s2[e[k] * P2 + t1];
            numb_step(p, bE, bX, tex, txx, teeN, txeN, teeN3F, txeN3F);
            --t1;
        }
#pragma unroll
        for (int k = 0; k < 4; ++k) {
            AST(&NB[lane * 8 + k],     bE[k]);
            AST(&NB[lane * 8 + 4 + k], bX[k]);
        }
        AST(&NB[512 + lane], __int_as_float(s));
    } else if (role == 2 && b < B) {
        // =================== DENOMINATOR FORWARD: t = 1..tm ================
        const int j  = lane & 7;
        const bool hi = (lane & 4) != 0;     // state >= 4 -> .y of stream pair
        const int rb = (j & 3) * P2;
        float Tr[8];
#pragma unroll
        for (int r = 0; r < 8; ++r)
            Tr[r] = fexp2(trans[((j - r) & 7) * S + j] * LOG2E);
        const float2 c00 = s2[rb];
        float al = fexp2(bos[j] * LOG2E) * (hi ? c00.y : c00.x);
        int sc = 0;
        int t = 1;
        if (t + 3 <= tm) {
            float2 a0 = s2[rb + t],     a1 = s2[rb + t + 1],
                   a2 = s2[rb + t + 2], a3 = s2[rb + t + 3];
            pin();
            while (t + 7 <= tm) {
                float2 b0 = s2[rb + t + 4], b1 = s2[rb + t + 5],
                       b2 = s2[rb + t + 6], b3 = s2[rb + t + 7];
                pin();
                al = denf_step(al, hi ? a0.y : a0.x, Tr);
                al = denf_step(al, hi ? a1.y : a1.x, Tr);
                al = denf_step(al, hi ? a2.y : a2.x, Tr);
                al = denf_step(al, hi ? a3.y : a3.x, Tr);
                sc += den_renorm(al);
                a0 = b0; a1 = b1; a2 = b2; a3 = b3;
                t += 4;
            }
            al = denf_step(al, hi ? a0.y : a0.x, Tr);
            al = denf_step(al, hi ? a1.y : a1.x, Tr);
            al = denf_step(al, hi ? a2.y : a2.x, Tr);
            al = denf_step(al, hi ? a3.y : a3.x, Tr);
            sc += den_renorm(al);
            t += 4;
        }
        while (t <= tm) {
            float2 cc = s2[rb + t];
            al = denf_step(al, hi ? cc.y : cc.x, Tr);
            ++t;
        }
        if (lane < 8) { scr[j] = al; ((int*)scr)[16 + j] = sc; }
    } else if (role == 3 && b < B) {
        // =================== DENOMINATOR BACKWARD: t = len-1..tm+1 =========
        const int j  = lane & 7;
        const bool hi = (lane & 4) != 0;
        const int rb = (j & 3) * P2;
        float TrB[8];
#pragma unroll
        for (int r = 0; r < 8; ++r)
            TrB[r] = fexp2(trans[j * S + ((j + r) & 7)] * LOG2E);
        float al = fexp2(eos[j] * LOG2E);
        int sc = 0;
        int t = len - 1;
        const int tlo = tm + 1;
        if (t - 3 >= tlo) {
            float2 a0 = s2[rb + t],     a1 = s2[rb + t - 1],
                   a2 = s2[rb + t - 2], a3 = s2[rb + t - 3];
            pin();
            while (t - 7 >= tlo) {
                float2 b0 = s2[rb + t - 4], b1 = s2[rb + t - 5],
                       b2 = s2[rb + t - 6], b3 = s2[rb + t - 7];
                pin();
                al = denb_step(al, hi ? a0.y : a0.x, TrB);
                al = denb_step(al, hi ? a1.y : a1.x, TrB);
                al = denb_step(al, hi ? a2.y : a2.x, TrB);
                al = denb_step(al, hi ? a3.y : a3.x, TrB);
                sc += den_renorm(al);
                a0 = b0; a1 = b1; a2 = b2; a3 = b3;
                t -= 4;
            }
            al = denb_step(al, hi ? a0.y : a0.x, TrB);
            al = denb_step(al, hi ? a1.y : a1.x, TrB);
            al = denb_step(al, hi ? a2.y : a2.x, TrB);
            al = denb_step(al, hi ? a3.y : a3.x, TrB);
            sc += den_renorm(al);
            t -= 4;
        }
        while (t >= tlo) {
            float2 cc = s2[rb + t];
            al = denb_step(al, hi ? cc.y : cc.x, TrB);
            --t;
        }
        if (lane < 8) { scr[8 + j] = al; ((int*)scr)[24 + j] = sc; }
    }

    // ---------------- per-sample den combine ----------------
    __syncthreads();
    if (role == 2 && lane < 8 && b < B) {
        const int j = lane;
        const float a  = fmaxf(scr[j],     1e-37f);
        const float bb = fmaxf(scr[8 + j], 1e-37f);
        float part = flog2(a) + flog2(bb)
                   + (float)(((int*)scr)[16 + j] + ((int*)scr)[24 + j]);
        part = lse2(part, __shfl_xor(part, 1, 64));
        part = lse2(part, __shfl_xor(part, 2, 64));
        part = lse2(part, __shfl_xor(part, 4, 64));
        if (j == 0) AST(&DEN[b], part);
    }

    // ---------------- ticket + winner combine ----------------
    __syncthreads();
    int* wflag = (int*)sm;
    if (tid == 0) {
        __threadfence();
        const int tk = atomicAdd(ticket, 1);
        wflag[0] = (tk == (int)gridDim.x - 1) ? 1 : 0;
    }
    __syncthreads();
    if (wflag[0] && tid < 64) {
        __threadfence();
        float acc = 0.0f;
        for (int bb2 = 0; bb2 < B; ++bb2) {
            const float* nf = ws + 16 + (size_t)bb2 * 576;
            const float* nb = ws + 16 + (size_t)B * 576 + (size_t)bb2 * 576;
            float v = 0.0f;
#pragma unroll
            for (int k = 0; k < 8; ++k)
                v = fmaf(ALD(&nf[lane * 8 + k]), ALD(&nb[lane * 8 + k]), v);
            const int st = __float_as_int(ALD(&nf[512 + lane]))
                         + __float_as_int(ALD(&nb[512 + lane]));
            float part = (v > 0.0f) ? (flog2(v) + (float)st) : -3.0e38f;
#pragma unroll
            for (int o = 1; o < 64; o <<= 1)
                part = lse2(part, __shfl_xor(part, o, 64));
            if (lane == 0) acc += ALD(&DEN[bb2]) - part;
        }
        if (lane == 0) out[0] = acc * (LN2 / (float)B);
    }
}

extern "C" void kernel_launch(void* const* d_in, const int* in_sizes, int n_in,
                              void* d_out, int out_size, void* d_ws, size_t ws_size,
                              hipStream_t stream)
{
    const float* em      = (const float*)d_in[0];
    const float* trans   = (const float*)d_in[1];
    const float* bos     = (const float*)d_in[2];
    const float* eos     = (const float*)d_in[3];
    const int*   lengths = (const int*)d_in[4];
    const int*   targets = (const int*)d_in[5];
    const int*   tlens   = (const int*)d_in[6];
    float* out = (float*)d_out;
    float* ws  = (float*)d_ws;

    const int B  = in_sizes[4];              // 16
    const int SS = in_sizes[1];              // 64
    int S = 1; while (S * S < SS) ++S;       // 8
    const int T = in_sizes[0] / (B * S);     // 2048
    const int L = in_sizes[5] / B;           // 256

    const int nblk = (B + 1) / 2;            // 8 blocks x 512 threads
    // 2 samples x 4 streams x (T+2) float2 = 16*(T+2) floats, + scratch
    const size_t shmem = (size_t)(16 * (T + 2) + 96) * sizeof(float);

    static bool attr_done = false;
    if (!attr_done) {
        (void)hipFuncSetAttribute((const void*)crf_fused,
                                  hipFuncAttributeMaxDynamicSharedMemorySize,
                                  (int)(140 * 1024));
        attr_done = true;
    }

    (void)hipMemsetAsync(ws, 0, 64, stream); // ticket
    hipLaunchKernelGGL(crf_fused, dim3(nblk), dim3(512), shmem, stream,
                       em, trans, bos, eos, lengths, targets, tlens,
                       ws, out, B, T, S, L);
}

// Round 2
// 155.551 us; speedup vs baseline: 1.2408x; 1.2408x over previous
//
#include <hip/hip_runtime.h>
#include <math.h>

// CTC-CRF NLL: mean_b( logZ_den(b) - logZ_num(b) ), B=16,T=2048,S=8,L=256.
//
// R13 = R11 geometry (48 blocks x 128, role per block, solo waves: proven
// 98us) + instruction diet in the scan loops. R12's role-fusion experiment
// showed waves do NOT co-schedule (per-wave x0.72 when paired) and implied
// ~60 issued instr/step (~2x the math) -> cut compiler overhead instead:
//  - num loops: even/odd 2-window unroll (16 steps/body) with symmetric
//    U/V float4[4][4] buffers -> no cross-iteration buffer-phi movs;
//    pointer-walked loads (pf += 4, imm offsets) instead of per-load
//    address rebuilds; prefetch distance a full window+boundary.
//  - den loops: R11 layout/order + R12-proven chunk double-buffer.
// Step order, boundary cadence, staging, combine identical to R11 ->
// bitwise-identical results expected (absmax 0).

#define LOG2E 1.4426950408889634f
#define LN2   0.69314718055994531f
#define CTL_WSHL1  0x130            // DPP wave_shl:1 (lane63 -> 0)
#define CTL_WSHR1  0x138            // DPP wave_shr:1 (lane0  -> 0)
#define CTL_ROR(r) (0x120 + (r))    // DPP row_ror:r

#define AST(p, v) __hip_atomic_store((p), (v), __ATOMIC_RELAXED, __HIP_MEMORY_SCOPE_AGENT)
#define ALD(p)    __hip_atomic_load((p), __ATOMIC_RELAXED, __HIP_MEMORY_SCOPE_AGENT)

template <int CTRL>
__device__ __forceinline__ float fdpp(float x) {
    return __int_as_float(__builtin_amdgcn_update_dpp(
        0, __float_as_int(x), CTRL, 0xF, 0xF, true));
}
template <int CTRL>
__device__ __forceinline__ int idpp(int x) {
    return __builtin_amdgcn_update_dpp(0, x, CTRL, 0xF, 0xF, true);
}

__device__ __forceinline__ void pin() {      // scheduler fence (MIR-level)
#if __has_builtin(__builtin_amdgcn_sched_barrier)
    __builtin_amdgcn_sched_barrier(0);
#else
    asm volatile("" ::: "memory");
#endif
}

__device__ __forceinline__ float fexp2(float x) {
#if __has_builtin(__builtin_amdgcn_exp2f)
    return __builtin_amdgcn_exp2f(x);
#else
    return exp2f(x);
#endif
}
__device__ __forceinline__ float flog2(float x) {
#if __has_builtin(__builtin_amdgcn_logf)
    return __builtin_amdgcn_logf(x);
#else
    return __log2f(x);
#endif
}
__device__ __forceinline__ float lse2(float a, float b) {   // log2(2^a+2^b)
    float m = fmaxf(a, b);
    float d = fminf(a, b) - m;
    return m + flog2(1.0f + fexp2(d));
}

struct NumC { float tee[4], txe[4], tex[4], txx[4]; };

// ---------------- forward numerator (proven) ----------------
__device__ __forceinline__ void numf_step(const float2* p, float* E, float* X,
                                          float teeF, float txeF, const NumC& c) {
    float nbE = fdpp<CTL_WSHR1>(E[3]);
    float nbX = fdpp<CTL_WSHR1>(X[3]);
    float nE3 = p[3].x * fmaf(E[2], c.tee[3], X[2] * c.txe[3]);
    float nX3 = p[3].y * fmaf(E[3], c.tex[3], X[3] * c.txx[3]);
    float nE0 = p[0].x * fmaf(nbE,  teeF,     nbX  * txeF);
    float nE1 = p[1].x * fmaf(E[0], c.tee[1], X[0] * c.txe[1]);
    float nE2 = p[2].x * fmaf(E[1], c.tee[2], X[1] * c.txe[2]);
    float nX0 = p[0].y * fmaf(E[0], c.tex[0], X[0] * c.txx[0]);
    float nX1 = p[1].y * fmaf(E[1], c.tex[1], X[1] * c.txx[1]);
    float nX2 = p[2].y * fmaf(E[2], c.tex[2], X[2] * c.txx[2]);
    E[0] = nE0; E[1] = nE1; E[2] = nE2; E[3] = nE3;
    X[0] = nX0; X[1] = nX1; X[2] = nX2; X[3] = nX3;
}

__device__ __forceinline__ void numf_boundary(float* E, float* X, int& s,
                                              float& teeF, float& txeF,
                                              int lane, const NumC& c) {
    float m = fmaxf(fmaxf(fmaxf(E[0], E[1]), fmaxf(E[2], E[3])),
                    fmaxf(fmaxf(X[0], X[1]), fmaxf(X[2], X[3])));
    const bool live = (m > 0.0f);
    const int ex = live ? ((int)(__float_as_uint(m) >> 23) - 126) : 0;
    s += ex;
    const int bs = idpp<CTL_WSHR1>(s);
    if (!live) s = bs;
    int d = (lane == 0) ? 0 : (bs - s);
    const int extra = (d > 30) ? d : 0;
    s += extra; d -= extra;
    const float fsc = ldexpf(1.0f, -(ex + extra));
#pragma unroll
    for (int k = 0; k < 4; ++k) { E[k] *= fsc; X[k] *= fsc; }
    const float fs0 = (lane == 0) ? 0.0f : ldexpf(1.0f, d);
    teeF = c.tee[0] * fs0;
    txeF = c.txe[0] * fs0;
}

// ---------------- backward numerator (proven) ----------------
__device__ __forceinline__ void numb_step(const float2* p, float* bE, float* bX,
                                          const float* tex, const float* txx,
                                          const float* teeN, const float* txeN,
                                          float teeN3F, float txeN3F) {
    float mm0 = p[0].x * bE[0];
    float mm1 = p[1].x * bE[1];
    float mm2 = p[2].x * bE[2];
    float mm3 = p[3].x * bE[3];
    float m10 = p[0].y * bX[0];
    float m11 = p[1].y * bX[1];
    float m12 = p[2].y * bX[2];
    float m13 = p[3].y * bX[3];
    float mup = fdpp<CTL_WSHL1>(mm0);
    float nE0 = fmaf(tex[0], m10, teeN[0] * mm1);
    float nX0 = fmaf(txx[0], m10, txeN[0] * mm1);
    float nE1 = fmaf(tex[1], m11, teeN[1] * mm2);
    float nE2 = fmaf(tex[2], m12, teeN[2] * mm3);
    float nE3 = fmaf(tex[3], m13, teeN3F   * mup);
    float nX1 = fmaf(txx[1], m11, txeN[1] * mm2);
    float nX2 = fmaf(txx[2], m12, txeN[2] * mm3);
    float nX3 = fmaf(txx[3], m13, txeN3F   * mup);
    bE[0] = nE0; bE[1] = nE1; bE[2] = nE2; bE[3] = nE3;
    bX[0] = nX0; bX[1] = nX1; bX[2] = nX2; bX[3] = nX3;
}

__device__ __forceinline__ void numb_boundary(float* bE, float* bX, int& s,
                                              float& teeN3F, float& txeN3F,
                                              int lane, float teeN3, float txeN3) {
    float m = fmaxf(fmaxf(fmaxf(bE[0], bE[1]), fmaxf(bE[2], bE[3])),
                    fmaxf(fmaxf(bX[0], bX[1]), fmaxf(bX[2], bX[3])));
    const bool live = (m > 0.0f);
    const int ex = live ? ((int)(__float_as_uint(m) >> 23) - 126) : 0;
    s += ex;
    const int bs = idpp<CTL_WSHL1>(s);
    if (!live) s = bs;
    int d = (lane == 63) ? 0 : (bs - s);
    const int extra = (d > 30) ? d : 0;
    s += extra; d -= extra;
    const float fsc = ldexpf(1.0f, -(ex + extra));
#pragma unroll
    for (int k = 0; k < 4; ++k) { bE[k] *= fsc; bX[k] *= fsc; }
    const float fs = (lane == 63) ? 0.0f : ldexpf(1.0f, d);
    teeN3F = teeN3 * fs;
    txeN3F = txeN3 * fs;
}

// ---------------- 4-step executors over float4 pairs ----------------
__device__ __forceinline__ void steps4_fwd(const float4 buf[4][2], float* E, float* X,
                                           float teeF, float txeF, const NumC& c) {
#pragma unroll
    for (int q = 0; q < 4; ++q) {
        float2 p[4];
#pragma unroll
        for (int k = 0; k < 4; ++k) {
            const float4 v = buf[k][q >> 1];
            p[k] = (q & 1) ? make_float2(v.z, v.w) : make_float2(v.x, v.y);
        }
        numf_step(p, E, X, teeF, txeF, c);
    }
}
__device__ __forceinline__ void steps4_bwd(const float4 buf[4][2], float* bE, float* bX,
                                           const float* tex, const float* txx,
                                           const float* teeN, const float* txeN,
                                           float teeN3F, float txeN3F) {
#pragma unroll
    for (int q = 0; q < 4; ++q) {            // t, t-1, t-2, t-3 (t odd)
        const int h = 1 - (q >> 1);
        float2 p[4];
#pragma unroll
        for (int k = 0; k < 4; ++k) {
            const float4 v = buf[k][h];
            p[k] = (q & 1) ? make_float2(v.x, v.y) : make_float2(v.z, v.w);
        }
        numb_step(p, bE, bX, tex, txx, teeN, txeN, teeN3F, txeN3F);
    }
}

// ---------------- 8-step windows over float4[4][4] buffers ----------------
__device__ __forceinline__ void win8_fwd(const float4 (&buf)[4][4], float* E, float* X,
                                         int& s, float& teeF, float& txeF,
                                         int lane, const NumC& c) {
    float4 h[4][2];
#pragma unroll
    for (int k = 0; k < 4; ++k) { h[k][0] = buf[k][0]; h[k][1] = buf[k][1]; }
    steps4_fwd(h, E, X, teeF, txeF, c);
#pragma unroll
    for (int k = 0; k < 4; ++k) { h[k][0] = buf[k][2]; h[k][1] = buf[k][3]; }
    steps4_fwd(h, E, X, teeF, txeF, c);
    numf_boundary(E, X, s, teeF, txeF, lane, c);
}
__device__ __forceinline__ void win8_bwd(const float4 (&buf)[4][4], float* bE, float* bX,
                                         int& s, float& teeN3F, float& txeN3F, int lane,
                                         const float* tex, const float* txx,
                                         const float* teeN, const float* txeN,
                                         float teeN3, float txeN3) {
    float4 h[4][2];
#pragma unroll
    for (int k = 0; k < 4; ++k) { h[k][0] = buf[k][2]; h[k][1] = buf[k][3]; }  // t1-3..t1
    steps4_bwd(h, bE, bX, tex, txx, teeN, txeN, teeN3F, txeN3F);
#pragma unroll
    for (int k = 0; k < 4; ++k) { h[k][0] = buf[k][0]; h[k][1] = buf[k][1]; }  // t1-7..t1-4
    steps4_bwd(h, bE, bX, tex, txx, teeN, txeN, teeN3F, txeN3F);
    numb_boundary(bE, bX, s, teeN3F, txeN3F, lane, teeN3, txeN3);
}

__device__ __forceinline__ void loadw(float4 (&D)[4][4], const float4* const (&p)[4]) {
#pragma unroll
    for (int k = 0; k < 4; ++k) {
#pragma unroll
        for (int j = 0; j < 4; ++j) D[k][j] = p[k][j];
    }
}

// ---------------- denominator steps (proven) ----------------
__device__ __forceinline__ float denf_step(float al, float emt, const float* Tr) {
    float v1 = fdpp<CTL_ROR(1)>(al);
    float v2 = fdpp<CTL_ROR(2)>(al);
    float v3 = fdpp<CTL_ROR(3)>(al);
    float v4 = fdpp<CTL_ROR(4)>(al);
    float v5 = fdpp<CTL_ROR(5)>(al);
    float v6 = fdpp<CTL_ROR(6)>(al);
    float v7 = fdpp<CTL_ROR(7)>(al);
    float q0 = fmaf(v1, Tr[1], al * Tr[0]);
    float q1 = fmaf(v3, Tr[3], v2 * Tr[2]);
    float q2 = fmaf(v5, Tr[5], v4 * Tr[4]);
    float q3 = fmaf(v7, Tr[7], v6 * Tr[6]);
    return ((q0 + q1) + (q2 + q3)) * emt;
}
__device__ __forceinline__ float denb_step(float al, float emt, const float* TrB) {
    float g  = al * emt;
    float v1 = fdpp<CTL_ROR(7)>(g);
    float v2 = fdpp<CTL_ROR(6)>(g);
    float v3 = fdpp<CTL_ROR(5)>(g);
    float v4 = fdpp<CTL_ROR(4)>(g);
    float v5 = fdpp<CTL_ROR(3)>(g);
    float v6 = fdpp<CTL_ROR(2)>(g);
    float v7 = fdpp<CTL_ROR(1)>(g);
    float q0 = fmaf(v1, TrB[1], g * TrB[0]);
    float q1 = fmaf(v3, TrB[3], v2 * TrB[2]);
    float q2 = fmaf(v5, TrB[5], v4 * TrB[4]);
    float q3 = fmaf(v7, TrB[7], v6 * TrB[6]);
    return (q0 + q1) + (q2 + q3);
}
__device__ __forceinline__ int den_renorm(float& al) {
    float mm = fmaxf(al, fdpp<CTL_ROR(4)>(al));
    mm = fmaxf(mm, fdpp<CTL_ROR(2)>(mm));
    mm = fmaxf(mm, fdpp<CTL_ROR(1)>(mm));
    const int ex = (int)(__float_as_uint(mm) >> 23) - 126;
    al = ldexpf(al, -ex);
    return ex;
}

extern "C" __global__ void __launch_bounds__(128)
crf_fused(const float* __restrict__ em, const float* __restrict__ trans,
          const float* __restrict__ bos, const float* __restrict__ eos,
          const int* __restrict__ lengths, const int* __restrict__ targets,
          const int* __restrict__ tlens,
          float* __restrict__ ws, float* __restrict__ out,
          int B, int T, int S, int L)
{
    extern __shared__ float sm[];
    const int bid  = blockIdx.x;
    const int tid  = threadIdx.x;
    const int lane = tid & 63;
    const int wv   = tid >> 6;
    const int half = S >> 1;                 // = 4
    const int role = bid / B;                // 0 num-fwd, 1 num-bwd, 2 den
    const int b    = bid % B;
    const float* gem = em + (size_t)b * T * S;
    const int len = lengths[b];
    const int tm  = (len - 1) >> 1;
    const int P2  = T + 2;                   // padded float2 pitch per stream
    const int Th2 = P2 >> 1;                 // float4 pitch per stream

    float* NF  = ws + 16 + (size_t)b * 576;
    float* NB  = ws + 16 + (size_t)B * 576 + (size_t)b * 576;
    float* DEN = ws + 16 + (size_t)(2 * B) * 576;
    int* ticket = (int*)ws;

    // ---------------- staging ----------------
    if (role < 2) {
        // padded transposed streams: s2[j*P2 + t] = (2^em[t][j], 2^em[t][j+4])
        float2* s2 = (float2*)sm;
        for (int t = tid; t < T; t += 128) {
            const float4* gr = (const float4*)(gem + t * S);
            float4 a = gr[0], c4 = gr[1];
            s2[0 * P2 + t] = make_float2(fexp2(a.x * LOG2E), fexp2(c4.x * LOG2E));
            s2[1 * P2 + t] = make_float2(fexp2(a.y * LOG2E), fexp2(c4.y * LOG2E));
            s2[2 * P2 + t] = make_float2(fexp2(a.z * LOG2E), fexp2(c4.z * LOG2E));
            s2[3 * P2 + t] = make_float2(fexp2(a.w * LOG2E), fexp2(c4.w * LOG2E));
        }
    } else {
        // row-interleaved for den: sm[t*8 + 2j+h]
        for (int t = tid; t < T; t += 128) {
            const float4* gr = (const float4*)(gem + t * S);
            float4 a = gr[0], c4 = gr[1];
            float4 w0, w1;
            w0.x = fexp2(a.x * LOG2E); w0.y = fexp2(c4.x * LOG2E);
            w0.z = fexp2(a.y * LOG2E); w0.w = fexp2(c4.y * LOG2E);
            w1.x = fexp2(a.z * LOG2E); w1.y = fexp2(c4.z * LOG2E);
            w1.z = fexp2(a.w * LOG2E); w1.w = fexp2(c4.w * LOG2E);
            ((float4*)sm)[t * 2]     = w0;
            ((float4*)sm)[t * 2 + 1] = w1;
        }
    }
    __syncthreads();

    if (role == 0 && wv == 0) {
        // =================== NUMERATOR FORWARD: t = 1..tm ===================
        const float2* s2 = (const float2*)sm;
        const float4* s4 = (const float4*)sm;
        const int u0 = lane * 4;
        int e[4], ep[4];
        const int base = b * L;
#pragma unroll
        for (int k = 0; k < 4; ++k) {
            int u = u0 + k;
            e[k] = targets[base + ((u < L) ? u : (L - 1))];
        }
        ep[0] = (u0 > 0) ? targets[base + u0 - 1] : e[0];
        ep[1] = e[0]; ep[2] = e[1]; ep[3] = e[2];
        NumC c;
#pragma unroll
        for (int k = 0; k < 4; ++k) {
            c.tee[k] = fexp2(trans[ep[k] * S + e[k]] * LOG2E);
            c.txe[k] = fexp2(trans[(ep[k] + half) * S + e[k]] * LOG2E);
            c.tex[k] = fexp2(trans[e[k] * S + e[k] + half] * LOG2E);
            c.txx[k] = fexp2(trans[(e[k] + half) * S + e[k] + half] * LOG2E);
        }
        float E[4] = {0.f,0.f,0.f,0.f}, X[4] = {0.f,0.f,0.f,0.f};
        int s = 0;
        if (lane == 0) E[0] = fexp2(bos[e[0]] * LOG2E) * s2[e[0] * P2].x;
        float teeF = (lane == 0) ? 0.0f : c.tee[0];
        float txeF = (lane == 0) ? 0.0f : c.txe[0];

        int t0 = 1;
        while (t0 <= tm && (t0 & 1)) {       // align to even t0
            float2 p[4];
#pragma unroll
            for (int k = 0; k < 4; ++k) p[k] = s2[e[k] * P2 + t0];
            numf_step(p, E, X, teeF, txeF, c);
            ++t0;
        }
        const int nw = (t0 <= tm) ? ((tm - t0 + 1) >> 3) : 0;
        if (nw >= 2) {
            const float4* pf[4];
#pragma unroll
            for (int k = 0; k < 4; ++k) pf[k] = s4 + e[k] * Th2 + (t0 >> 1);
            float4 U[4][4], V[4][4];
            loadw(U, pf);                    // window 0
#pragma unroll
            for (int k = 0; k < 4; ++k) pf[k] += 4;
            pin();
            const int di = nw >> 1;
            for (int i = 0; i < di; ++i) {
                loadw(V, pf);                // window 2i+1
#pragma unroll
                for (int k = 0; k < 4; ++k) pf[k] += 4;
                pin();
                win8_fwd(U, E, X, s, teeF, txeF, lane, c);
                loadw(U, pf);                // window 2i+2 (overshoot-safe: padded)
#pragma unroll
                for (int k = 0; k < 4; ++k) pf[k] += 4;
                pin();
                win8_fwd(V, E, X, s, teeF, txeF, lane, c);
                t0 += 16;
            }
        }
        while (t0 + 7 <= tm) {               // leftover window(s)
            float4 D[4][4];
#pragma unroll
            for (int k = 0; k < 4; ++k) {
                const float4* q = s4 + e[k] * Th2 + (t0 >> 1);
#pragma unroll
                for (int j = 0; j < 4; ++j) D[k][j] = q[j];
            }
            pin();
            win8_fwd(D, E, X, s, teeF, txeF, lane, c);
            t0 += 8;
        }
        while (t0 <= tm) {                   // tail
            float2 p[4];
#pragma unroll
            for (int k = 0; k < 4; ++k) p[k] = s2[e[k] * P2 + t0];
            numf_step(p, E, X, teeF, txeF, c);
            ++t0;
        }
#pragma unroll
        for (int k = 0; k < 4; ++k) {
            AST(&NF[lane * 8 + k],     E[k]);
            AST(&NF[lane * 8 + 4 + k], X[k]);
        }
        AST(&NF[512 + lane], __int_as_float(s));
    } else if (role == 1 && wv == 0) {
        // =================== NUMERATOR BACKWARD: t = len-1..tm+1 ===========
        const float2* s2 = (const float2*)sm;
        const float4* s4 = (const float4*)sm;
        const int u0 = lane * 4;
        int e[5];
        const int base = b * L;
#pragma unroll
        for (int k = 0; k < 5; ++k) {
            int u = u0 + k;
            e[k] = targets[base + ((u < L) ? u : (L - 1))];
        }
        float tex[4], txx[4], teeN[4], txeN[4];
#pragma unroll
        for (int k = 0; k < 4; ++k) {
            tex[k]  = fexp2(trans[e[k] * S + e[k] + half] * LOG2E);
            txx[k]  = fexp2(trans[(e[k] + half) * S + e[k] + half] * LOG2E);
            teeN[k] = fexp2(trans[e[k] * S + e[k + 1]] * LOG2E);
            txeN[k] = fexp2(trans[(e[k] + half) * S + e[k + 1]] * LOG2E);
        }
        if (lane == 63) { teeN[3] = 0.0f; txeN[3] = 0.0f; }
        float bE[4] = {0.f,0.f,0.f,0.f}, bX[4] = {0.f,0.f,0.f,0.f};
        const int uf = tlens[b] - 1;
        if (lane == (uf >> 2)) {
            const int kf = uf & 3;
            bE[kf] = fexp2(eos[e[kf]] * LOG2E);
            bX[kf] = fexp2(eos[e[kf] + half] * LOG2E);
        }
        int s = 0;
        float teeN3F = teeN[3], txeN3F = txeN[3];

        int t1 = len - 1;
        const int tlo = tm + 1;
        while (t1 >= tlo && !(t1 & 1)) {     // align to odd t1
            float2 p[4];
#pragma unroll
            for (int k = 0; k < 4; ++k) p[k] = s2[e[k] * P2 + t1];
            numb_step(p, bE, bX, tex, txx, teeN, txeN, teeN3F, txeN3F);
            --t1;
        }
        const int nw = (t1 >= tlo) ? ((t1 - tlo + 1) >> 3) : 0;
        if (nw >= 2 && tlo >= 16) {          // tlo guard: overshoot reads stay >= 0
            const float4* pb[4];
#pragma unroll
            for (int k = 0; k < 4; ++k) pb[k] = s4 + e[k] * Th2 + ((t1 - 7) >> 1);
            float4 U[4][4], V[4][4];
            loadw(U, pb);                    // window 0 (t1-7..t1)
#pragma unroll
            for (int k = 0; k < 4; ++k) pb[k] -= 4;
            pin();
            const int di = nw >> 1;
            for (int i = 0; i < di; ++i) {
                loadw(V, pb);                // window 2i+1
#pragma unroll
                for (int k = 0; k < 4; ++k) pb[k] -= 4;
                pin();
                win8_bwd(U, bE, bX, s, teeN3F, txeN3F, lane,
                         tex, txx, teeN, txeN, teeN[3], txeN[3]);
                loadw(U, pb);                // window 2i+2 (overshoot-safe)
#pragma unroll
                for (int k = 0; k < 4; ++k) pb[k] -= 4;
                pin();
                win8_bwd(V, bE, bX, s, teeN3F, txeN3F, lane,
                         tex, txx, teeN, txeN, teeN[3], txeN[3]);
                t1 -= 16;
            }
        }
        while (t1 - 7 >= tlo) {              // leftover window(s)
            float4 D[4][4];
#pragma unroll
            for (int k = 0; k < 4; ++k) {
                const float4* q = s4 + e[k] * Th2 + ((t1 - 7) >> 1);
#pragma unroll
                for (int j = 0; j < 4; ++j) D[k][j] = q[j];
            }
            pin();
            win8_bwd(D, bE, bX, s, teeN3F, txeN3F, lane,
                     tex, txx, teeN, txeN, teeN[3], txeN[3]);
            t1 -= 8;
        }
        while (t1 >= tlo) {                  // tail
            float2 p[4];
#pragma unroll
            for (int k = 0; k < 4; ++k) p[k] = s2[e[k] * P2 + t1];
            numb_step(p, bE, bX, tex, txx, teeN, txeN, teeN3F, txeN3F);
            --t1;
        }
#pragma unroll
        for (int k = 0; k < 4; ++k) {
            AST(&NB[lane * 8 + k],     bE[k]);
            AST(&NB[lane * 8 + 4 + k], bX[k]);
        }
        AST(&NB[512 + lane], __int_as_float(s));
    } else if (role == 2) {
        // =================== DENOMINATOR (2 waves) ===================
        float* denF  = sm + T * 8 + 16;
        float* denB  = denF + 8;
        int*   denFs = (int*)(denB + 8);
        int*   denBs = denFs + 8;
        const int j  = lane & 7;
        const int jj = ((j & 3) << 1) + (j >> 2);
        if (wv == 0) {
            float Tr[8];
#pragma unroll
            for (int r = 0; r < 8; ++r)
                Tr[r] = fexp2(trans[((j - r) & 7) * S + j] * LOG2E);
            float al = fexp2(bos[j] * LOG2E) * sm[jj];
            int sc = 0;
            int t = 1;
            if (t + 3 <= tm) {
                float c0 = sm[t * 8 + jj];
                float c1 = sm[(t + 1) * 8 + jj];
                float c2 = sm[(t + 2) * 8 + jj];
                float c3 = sm[(t + 3) * 8 + jj];
                pin();
                while (t + 7 <= tm) {
                    float d0 = sm[(t + 4) * 8 + jj];
                    float d1 = sm[(t + 5) * 8 + jj];
                    float d2 = sm[(t + 6) * 8 + jj];
                    float d3 = sm[(t + 7) * 8 + jj];
                    pin();
                    al = denf_step(al, c0, Tr);
                    al = denf_step(al, c1, Tr);
                    al = denf_step(al, c2, Tr);
                    al = denf_step(al, c3, Tr);
                    sc += den_renorm(al);
                    c0 = d0; c1 = d1; c2 = d2; c3 = d3;
                    t += 4;
                }
                al = denf_step(al, c0, Tr);
                al = denf_step(al, c1, Tr);
                al = denf_step(al, c2, Tr);
                al = denf_step(al, c3, Tr);
                sc += den_renorm(al);
                t += 4;
            }
            while (t <= tm) { al = denf_step(al, sm[t * 8 + jj], Tr); ++t; }
            if (lane < 8) { denF[j] = al; denFs[j] = sc; }
        } else {
            float TrB[8];
#pragma unroll
            for (int r = 0; r < 8; ++r)
                TrB[r] = fexp2(trans[j * S + ((j + r) & 7)] * LOG2E);
            float al = fexp2(eos[j] * LOG2E);
            int sc = 0;
            int t = len - 1;
            const int tlo = tm + 1;
            if (t - 3 >= tlo) {
                float c0 = sm[t * 8 + jj];
                float c1 = sm[(t - 1) * 8 + jj];
                float c2 = sm[(t - 2) * 8 + jj];
                float c3 = sm[(t - 3) * 8 + jj];
                pin();
                while (t - 7 >= tlo) {
                    float d0 = sm[(t - 4) * 8 + jj];
                    float d1 = sm[(t - 5) * 8 + jj];
                    float d2 = sm[(t - 6) * 8 + jj];
                    float d3 = sm[(t - 7) * 8 + jj];
                    pin();
                    al = denb_step(al, c0, TrB);
                    al = denb_step(al, c1, TrB);
                    al = denb_step(al, c2, TrB);
                    al = denb_step(al, c3, TrB);
                    sc += den_renorm(al);
                    c0 = d0; c1 = d1; c2 = d2; c3 = d3;
                    t -= 4;
                }
                al = denb_step(al, c0, TrB);
                al = denb_step(al, c1, TrB);
                al = denb_step(al, c2, TrB);
                al = denb_step(al, c3, TrB);
                sc += den_renorm(al);
                t -= 4;
            }
            while (t >= tlo) { al = denb_step(al, sm[t * 8 + jj], TrB); --t; }
            if (lane < 8) { denB[j] = al; denBs[j] = sc; }
        }
        __syncthreads();
        if (wv == 0 && lane < 8) {
            const float a  = fmaxf(denF[j], 1e-37f);
            const float bb = fmaxf(denB[j], 1e-37f);
            float part = flog2(a) + flog2(bb) + (float)(denFs[j] + denBs[j]);
            part = lse2(part, __shfl_xor(part, 1, 64));
            part = lse2(part, __shfl_xor(part, 2, 64));
            part = lse2(part, __shfl_xor(part, 4, 64));
            if (j == 0) AST(&DEN[b], part);
        }
    }

    // ---------------- ticket + winner combine ----------------
    __syncthreads();
    int* wflag = (int*)sm;
    if (tid == 0) {
        __threadfence();
        const int tk = atomicAdd(ticket, 1);
        wflag[0] = (tk == 3 * B - 1) ? 1 : 0;
    }
    __syncthreads();
    if (wflag[0] && tid < 64) {
        __threadfence();
        float acc = 0.0f;
        for (int bb2 = 0; bb2 < B; ++bb2) {
            const float* nf = ws + 16 + (size_t)bb2 * 576;
            const float* nb = ws + 16 + (size_t)B * 576 + (size_t)bb2 * 576;
            float v = 0.0f;
#pragma unroll
            for (int k = 0; k < 8; ++k)
                v = fmaf(ALD(&nf[lane * 8 + k]), ALD(&nb[lane * 8 + k]), v);
            const int st = __float_as_int(ALD(&nf[512 + lane]))
                         + __float_as_int(ALD(&nb[512 + lane]));
            float part = (v > 0.0f) ? (flog2(v) + (float)st) : -3.0e38f;
#pragma unroll
            for (int o = 1; o < 64; o <<= 1)
                part = lse2(part, __shfl_xor(part, o, 64));
            if (lane == 0) acc += ALD(&DEN[bb2]) - part;
        }
        if (lane == 0) out[0] = acc * (LN2 / (float)B);
    }
}

extern "C" void kernel_launch(void* const* d_in, const int* in_sizes, int n_in,
                              void* d_out, int out_size, void* d_ws, size_t ws_size,
                              hipStream_t stream)
{
    const float* em      = (const float*)d_in[0];
    const float* trans   = (const float*)d_in[1];
    const float* bos     = (const float*)d_in[2];
    const float* eos     = (const float*)d_in[3];
    const int*   lengths = (const int*)d_in[4];
    const int*   targets = (const int*)d_in[5];
    const int*   tlens   = (const int*)d_in[6];
    float* out = (float*)d_out;
    float* ws  = (float*)d_ws;

    const int B  = in_sizes[4];              // 16
    const int SS = in_sizes[1];              // 64
    int S = 1; while (S * S < SS) ++S;       // 8
    const int T = in_sizes[0] / (B * S);     // 2048
    const int L = in_sizes[5] / B;           // 256

    // padded streams need 8*(T+2) floats; den needs T*8 + small scratch
    const size_t shmem = (size_t)(T * 8 + 80) * sizeof(float);

    static bool attr_done = false;
    if (!attr_done) {
        (void)hipFuncSetAttribute((const void*)crf_fused,
                                  hipFuncAttributeMaxDynamicSharedMemorySize,
                                  (int)(96 * 1024));
        attr_done = true;
    }

    (void)hipMemsetAsync(ws, 0, 64, stream); // ticket
    hipLaunchKernelGGL(crf_fused, dim3(3 * B), dim3(128), shmem, stream,
                       em, trans, bos, eos, lengths, targets, tlens,
                       ws, out, B, T, S, L);
}

// Round 4
// 150.752 us; speedup vs baseline: 1.2803x; 1.0318x over previous
//
#include <hip/hip_runtime.h>
#include <math.h>

// CTC-CRF NLL: mean_b( logZ_den(b) - logZ_num(b) ), B=16,T=2048,S=8,L=256.
//
// R15 = R14 with the backward-pipeline ring-index bug fixed.
// R14 introduced the 2-wave symbol-split pipeline for the num scans
// (wave0: symbols 0..127, wave1: 128..255; producer runs one 16-step chunk
// ahead, boundary state crosses via an LDS ring, __syncthreads per phase).
// BUG in R14's NBW_STEP: the bwd consumer (wave0, lane 63) needs the
// producer's LANE 0 values (symbol 128 = left edge of wave1's range):
//   rm = rM[k*64 + 0], rs = rS[slot*64 + 0]
// but R14 read "+63" (copied from the fwd macro, where lane 63 is correct).
// Fixed here. Everything else identical to R14:
//  - fwd: consumer lane0 reads producer lane63 ring slots (correct).
//  - all scaling power-of-2-exact; lse2 association ulp-level only.
//  - den role, staging, ticket combine: proven R13 code.

#define LOG2E 1.4426950408889634f
#define LN2   0.69314718055994531f
#define CTL_WSHL1  0x130            // DPP wave_shl:1 (lane63 -> 0)
#define CTL_WSHR1  0x138            // DPP wave_shr:1 (lane0  -> 0)
#define CTL_ROR(r) (0x120 + (r))    // DPP row_ror:r

#define AST(p, v) __hip_atomic_store((p), (v), __ATOMIC_RELAXED, __HIP_MEMORY_SCOPE_AGENT)
#define ALD(p)    __hip_atomic_load((p), __ATOMIC_RELAXED, __HIP_MEMORY_SCOPE_AGENT)

template <int CTRL>
__device__ __forceinline__ float fdpp(float x) {
    return __int_as_float(__builtin_amdgcn_update_dpp(
        0, __float_as_int(x), CTRL, 0xF, 0xF, true));
}
template <int CTRL>
__device__ __forceinline__ int idpp(int x) {
    return __builtin_amdgcn_update_dpp(0, x, CTRL, 0xF, 0xF, true);
}

__device__ __forceinline__ void pin() {      // scheduler fence (MIR-level)
#if __has_builtin(__builtin_amdgcn_sched_barrier)
    __builtin_amdgcn_sched_barrier(0);
#else
    asm volatile("" ::: "memory");
#endif
}

__device__ __forceinline__ float fexp2(float x) {
#if __has_builtin(__builtin_amdgcn_exp2f)
    return __builtin_amdgcn_exp2f(x);
#else
    return exp2f(x);
#endif
}
__device__ __forceinline__ float flog2(float x) {
#if __has_builtin(__builtin_amdgcn_logf)
    return __builtin_amdgcn_logf(x);
#else
    return __log2f(x);
#endif
}
__device__ __forceinline__ float lse2(float a, float b) {   // log2(2^a+2^b)
    float m = fmaxf(a, b);
    float d = fminf(a, b) - m;
    return m + flog2(1.0f + fexp2(d));
}

// ================= numerator forward: one step + inline boundary ==========
// CONS=false: producer (wave0, symbols 0..127), writes ring.
// CONS=true : consumer (wave1, symbols 128..255), reads ring at lane 0
//             (needs producer lane 63 = symbol 127).
#define NFW_STEP {                                                          \
    float2 q0 = st0[tb + k + 1], q1 = st1[tb + k + 1];                      \
    float2 rv = make_float2(0.0f, 0.0f);                                    \
    if (CONS) rv = rEX[k * 64 + 63];                                        \
    float nbE = fdpp<CTL_WSHR1>(E[1]);                                      \
    float nbX = fdpp<CTL_WSHR1>(X[1]);                                      \
    if (CONS && l0) { nbE = rv.x; nbX = rv.y; }                             \
    float nE0 = p0.x * fmaf(nbE,  teeF, nbX  * txeF);                       \
    float nE1 = p1.x * fmaf(E[0], tee1, X[0] * txe1);                       \
    float nX0 = p0.y * fmaf(E[0], tex0, X[0] * txx0);                       \
    float nX1 = p1.y * fmaf(E[1], tex1, X[1] * txx1);                       \
    E[0] = nE0; E[1] = nE1; X[0] = nX0; X[1] = nX1;                         \
    if (!CONS) rEX[(k + 1) * 64 + lane] = make_float2(E[1], X[1]);          \
    if ((k & 7) == 7) {                                                     \
        int rs = 0;                                                         \
        if (CONS) rs = rS[(k >> 3) * 64 + 63];                              \
        float m = fmaxf(fmaxf(E[0], E[1]), fmaxf(X[0], X[1]));              \
        const bool live = (m > 0.0f);                                       \
        const int ex = live ? ((int)(__float_as_uint(m) >> 23) - 126) : 0;  \
        s += ex;                                                            \
        int bs = idpp<CTL_WSHR1>(s);                                        \
        if (CONS && l0) bs = rs;                                            \
        if (!live) s = bs;                                                  \
        int d = (g == 0) ? 0 : (bs - s);                                    \
        const int extra = (d > 30) ? d : 0;                                 \
        s += extra; d -= extra;                                             \
        const float fsc = ldexpf(1.0f, -(ex + extra));                      \
        E[0] *= fsc; E[1] *= fsc; X[0] *= fsc; X[1] *= fsc;                 \
        const float fs0 = (g == 0) ? 0.0f : ldexpf(1.0f, d);                \
        teeF = tee0 * fs0; txeF = txe0 * fs0;                               \
        if (!CONS) { rS[(k >> 3) * 64 + lane] = s;                          \
                     rEX[(k + 1) * 64 + lane] = make_float2(E[1], X[1]); }  \
    }                                                                       \
    p0 = q0; p1 = q1; }

template <bool CONS>
__device__ __forceinline__ void nfwd_chunk(
    const float2* st0, const float2* st1,
    float (&E)[2], float (&X)[2], int& s, float& teeF, float& txeF,
    float tee0, float txe0, float tee1, float txe1,
    float tex0, float txx0, float tex1, float txx1,
    int tb, int n, int g, int lane, float2* rEX, int* rS)
{
    const bool l0 = (lane == 0);
    if (!CONS) rEX[lane] = make_float2(E[1], X[1]);   // carry-in slot 0
    float2 p0 = st0[tb], p1 = st1[tb];
    if (n == 16) {
#pragma unroll
        for (int k = 0; k < 16; ++k) NFW_STEP
    } else {
        for (int k = 0; k < n; ++k) NFW_STEP
    }
}

// ================= numerator backward: one step + inline boundary =========
// CONS=false: producer (wave1, symbols 128..255), writes ring (mm0, s).
// CONS=true : consumer (wave0, symbols 0..127), reads ring at lane 63
//             (needs producer LANE 0 = symbol 128).  [R14 bug: read +63]
#define NBW_STEP {                                                          \
    float2 q0 = st0[tb - k - 1], q1 = st1[tb - k - 1];                      \
    float rm = 0.0f;                                                        \
    if (CONS) rm = rM[k * 64];                                              \
    float mm0 = p0.x * bE[0];                                               \
    float mm1 = p1.x * bE[1];                                               \
    float m10 = p0.y * bX[0];                                               \
    float m11 = p1.y * bX[1];                                               \
    float mup = fdpp<CTL_WSHL1>(mm0);                                       \
    if (CONS && l63) mup = rm;                                              \
    if (!CONS) rM[k * 64 + lane] = mm0;                                     \
    float nE0 = fmaf(tex0, m10, teeN0 * mm1);                               \
    float nX0 = fmaf(txx0, m10, txeN0 * mm1);                               \
    float nE1 = fmaf(tex1, m11, teeN1F * mup);                              \
    float nX1 = fmaf(txx1, m11, txeN1F * mup);                              \
    bE[0] = nE0; bE[1] = nE1; bX[0] = nX0; bX[1] = nX1;                     \
    if ((k & 7) == 7) {                                                     \
        int rs = 0;                                                         \
        if (CONS) rs = rS[(k >> 3) * 64];                                   \
        float m = fmaxf(fmaxf(bE[0], bE[1]), fmaxf(bX[0], bX[1]));          \
        const bool live = (m > 0.0f);                                       \
        const int ex = live ? ((int)(__float_as_uint(m) >> 23) - 126) : 0;  \
        s += ex;                                                            \
        int bs = idpp<CTL_WSHL1>(s);                                        \
        if (CONS && l63) bs = rs;                                           \
        if (!live) s = bs;                                                  \
        int d = (g == 127) ? 0 : (bs - s);                                  \
        const int extra = (d > 30) ? d : 0;                                 \
        s += extra; d -= extra;                                             \
        const float fsc = ldexpf(1.0f, -(ex + extra));                      \
        bE[0] *= fsc; bE[1] *= fsc; bX[0] *= fsc; bX[1] *= fsc;             \
        const float fs = (g == 127) ? 0.0f : ldexpf(1.0f, d);               \
        teeN1F = teeN1 * fs; txeN1F = txeN1 * fs;                           \
        if (!CONS) rS[(k >> 3) * 64 + lane] = s;                            \
    }                                                                       \
    p0 = q0; p1 = q1; }

template <bool CONS>
__device__ __forceinline__ void nbwd_chunk(
    const float2* st0, const float2* st1,
    float (&bE)[2], float (&bX)[2], int& s, float& teeN1F, float& txeN1F,
    float teeN0, float txeN0, float teeN1, float txeN1,
    float tex0, float txx0, float tex1, float txx1,
    int tb, int n, int g, int lane, float* rM, int* rS)
{
    const bool l63 = (lane == 63);
    float2 p0 = st0[tb], p1 = st1[tb];
    if (n == 16) {
#pragma unroll
        for (int k = 0; k < 16; ++k) NBW_STEP
    } else {
        for (int k = 0; k < n; ++k) NBW_STEP
    }
}

// ---------------- denominator steps (proven) ----------------
__device__ __forceinline__ float denf_step(float al, float emt, const float* Tr) {
    float v1 = fdpp<CTL_ROR(1)>(al);
    float v2 = fdpp<CTL_ROR(2)>(al);
    float v3 = fdpp<CTL_ROR(3)>(al);
    float v4 = fdpp<CTL_ROR(4)>(al);
    float v5 = fdpp<CTL_ROR(5)>(al);
    float v6 = fdpp<CTL_ROR(6)>(al);
    float v7 = fdpp<CTL_ROR(7)>(al);
    float q0 = fmaf(v1, Tr[1], al * Tr[0]);
    float q1 = fmaf(v3, Tr[3], v2 * Tr[2]);
    float q2 = fmaf(v5, Tr[5], v4 * Tr[4]);
    float q3 = fmaf(v7, Tr[7], v6 * Tr[6]);
    return ((q0 + q1) + (q2 + q3)) * emt;
}
__device__ __forceinline__ float denb_step(float al, float emt, const float* TrB) {
    float g  = al * emt;
    float v1 = fdpp<CTL_ROR(7)>(g);
    float v2 = fdpp<CTL_ROR(6)>(g);
    float v3 = fdpp<CTL_ROR(5)>(g);
    float v4 = fdpp<CTL_ROR(4)>(g);
    float v5 = fdpp<CTL_ROR(3)>(g);
    float v6 = fdpp<CTL_ROR(2)>(g);
    float v7 = fdpp<CTL_ROR(1)>(g);
    float q0 = fmaf(v1, TrB[1], g * TrB[0]);
    float q1 = fmaf(v3, TrB[3], v2 * TrB[2]);
    float q2 = fmaf(v5, TrB[5], v4 * TrB[4]);
    float q3 = fmaf(v7, TrB[7], v6 * TrB[6]);
    return (q0 + q1) + (q2 + q3);
}
__device__ __forceinline__ int den_renorm(float& al) {
    float mm = fmaxf(al, fdpp<CTL_ROR(4)>(al));
    mm = fmaxf(mm, fdpp<CTL_ROR(2)>(mm));
    mm = fmaxf(mm, fdpp<CTL_ROR(1)>(mm));
    const int ex = (int)(__float_as_uint(mm) >> 23) - 126;
    al = ldexpf(al, -ex);
    return ex;
}

extern "C" __global__ void __launch_bounds__(128)
crf_fused(const float* __restrict__ em, const float* __restrict__ trans,
          const float* __restrict__ bos, const float* __restrict__ eos,
          const int* __restrict__ lengths, const int* __restrict__ targets,
          const int* __restrict__ tlens,
          float* __restrict__ ws, float* __restrict__ out,
          int B, int T, int S, int L)
{
    extern __shared__ float sm[];
    const int bid  = blockIdx.x;
    const int tid  = threadIdx.x;
    const int lane = tid & 63;
    const int wv   = tid >> 6;
    const int half = S >> 1;                 // = 4
    const int role = bid / B;                // 0 num-fwd, 1 num-bwd, 2 den
    const int b    = bid % B;
    const float* gem = em + (size_t)b * T * S;
    const int len = lengths[b];
    const int tm  = (len - 1) >> 1;
    const int P2  = T + 2;                   // padded float2 pitch per stream
    const int RINGF = 8 * P2;                // ring offset (floats)

    float* NF  = ws + 16 + (size_t)b * 640;
    float* NB  = ws + 16 + (size_t)B * 640 + (size_t)b * 640;
    float* DEN = ws + 16 + (size_t)(2 * B) * 640;
    int* ticket = (int*)ws;

    // ---------------- staging ----------------
    if (role < 2) {
        // padded transposed streams: s2[j*P2 + t] = (2^em[t][j], 2^em[t][j+4])
        float2* s2 = (float2*)sm;
        for (int t = tid; t < T; t += 128) {
            const float4* gr = (const float4*)(gem + t * S);
            float4 a = gr[0], c4 = gr[1];
            s2[0 * P2 + t] = make_float2(fexp2(a.x * LOG2E), fexp2(c4.x * LOG2E));
            s2[1 * P2 + t] = make_float2(fexp2(a.y * LOG2E), fexp2(c4.y * LOG2E));
            s2[2 * P2 + t] = make_float2(fexp2(a.z * LOG2E), fexp2(c4.z * LOG2E));
            s2[3 * P2 + t] = make_float2(fexp2(a.w * LOG2E), fexp2(c4.w * LOG2E));
        }
    } else {
        // row-interleaved for den: sm[t*8 + 2j+h]
        for (int t = tid; t < T; t += 128) {
            const float4* gr = (const float4*)(gem + t * S);
            float4 a = gr[0], c4 = gr[1];
            float4 w0, w1;
            w0.x = fexp2(a.x * LOG2E); w0.y = fexp2(c4.x * LOG2E);
            w0.z = fexp2(a.y * LOG2E); w0.w = fexp2(c4.y * LOG2E);
            w1.x = fexp2(a.z * LOG2E); w1.y = fexp2(c4.z * LOG2E);
            w1.z = fexp2(a.w * LOG2E); w1.w = fexp2(c4.w * LOG2E);
            ((float4*)sm)[t * 2]     = w0;
            ((float4*)sm)[t * 2 + 1] = w1;
        }
    }
    __syncthreads();

    if (role == 0) {
        // ===== NUMERATOR FORWARD, 2-wave symbol-split pipeline: t=1..tm =====
        const float2* s2v = (const float2*)sm;
        const int g   = (wv << 6) + lane;    // global lane 0..127
        const int u0g = g * 2;
        const int base = b * L;
        const int e0 = targets[base + ((u0g     < L) ? u0g     : (L - 1))];
        const int e1 = targets[base + ((u0g + 1 < L) ? u0g + 1 : (L - 1))];
        const int ep = (u0g > 0) ? targets[base + u0g - 1] : e0;
        const float tee0 = fexp2(trans[ep * S + e0] * LOG2E);
        const float txe0 = fexp2(trans[(ep + half) * S + e0] * LOG2E);
        const float tee1 = fexp2(trans[e0 * S + e1] * LOG2E);
        const float txe1 = fexp2(trans[(e0 + half) * S + e1] * LOG2E);
        const float tex0 = fexp2(trans[e0 * S + e0 + half] * LOG2E);
        const float txx0 = fexp2(trans[(e0 + half) * S + e0 + half] * LOG2E);
        const float tex1 = fexp2(trans[e1 * S + e1 + half] * LOG2E);
        const float txx1 = fexp2(trans[(e1 + half) * S + e1 + half] * LOG2E);
        const float2* st0 = s2v + e0 * P2;
        const float2* st1 = s2v + e1 * P2;
        float E[2] = {0.f, 0.f}, X[2] = {0.f, 0.f};
        int s = 0;
        if (g == 0) E[0] = fexp2(bos[e0] * LOG2E) * st0[0].x;
        float teeF = (g == 0) ? 0.0f : tee0;
        float txeF = (g == 0) ? 0.0f : txe0;

        float2* ringEX = (float2*)(sm + RINGF);       // [2][17][64]
        int*    ringS  = (int*)(sm + RINGF + 4352);   // [2][2][64]
        const int NCH = (tm + 15) >> 4;
        for (int ph = 0; ph <= NCH; ++ph) {
            const int ci = (wv == 0) ? ph : ph - 1;   // producer = wave0
            if (ci >= 0 && ci < NCH) {
                const int tb = 1 + (ci << 4);
                int n = tm - tb + 1; if (n > 16) n = 16;
                float2* rEX = ringEX + (ci & 1) * (17 * 64);
                int*    rS  = ringS  + (ci & 1) * 128;
                if (wv == 0)
                    nfwd_chunk<false>(st0, st1, E, X, s, teeF, txeF,
                                      tee0, txe0, tee1, txe1,
                                      tex0, txx0, tex1, txx1,
                                      tb, n, g, lane, rEX, rS);
                else
                    nfwd_chunk<true>(st0, st1, E, X, s, teeF, txeF,
                                     tee0, txe0, tee1, txe1,
                                     tex0, txx0, tex1, txx1,
                                     tb, n, g, lane, rEX, rS);
            }
            __syncthreads();
        }
        AST(&NF[g * 4 + 0], E[0]);
        AST(&NF[g * 4 + 1], E[1]);
        AST(&NF[g * 4 + 2], X[0]);
        AST(&NF[g * 4 + 3], X[1]);
        AST(&NF[512 + g], __int_as_float(s));
    } else if (role == 1) {
        // ===== NUMERATOR BACKWARD, 2-wave pipeline: t = len-1 .. tm+1 =====
        const float2* s2v = (const float2*)sm;
        const int g   = (wv << 6) + lane;
        const int u0g = g * 2;
        const int base = b * L;
        const int e0 = targets[base + ((u0g     < L) ? u0g     : (L - 1))];
        const int e1 = targets[base + ((u0g + 1 < L) ? u0g + 1 : (L - 1))];
        const int e2 = targets[base + ((u0g + 2 < L) ? u0g + 2 : (L - 1))];
        const float tex0 = fexp2(trans[e0 * S + e0 + half] * LOG2E);
        const float txx0 = fexp2(trans[(e0 + half) * S + e0 + half] * LOG2E);
        const float tex1 = fexp2(trans[e1 * S + e1 + half] * LOG2E);
        const float txx1 = fexp2(trans[(e1 + half) * S + e1 + half] * LOG2E);
        const float teeN0 = fexp2(trans[e0 * S + e1] * LOG2E);
        const float txeN0 = fexp2(trans[(e0 + half) * S + e1] * LOG2E);
        float teeN1 = fexp2(trans[e1 * S + e2] * LOG2E);
        float txeN1 = fexp2(trans[(e1 + half) * S + e2] * LOG2E);
        if (g == 127) { teeN1 = 0.0f; txeN1 = 0.0f; }
        const float2* st0 = s2v + e0 * P2;
        const float2* st1 = s2v + e1 * P2;
        float bE[2] = {0.f, 0.f}, bX[2] = {0.f, 0.f};
        const int uf = tlens[b] - 1;
        if (g == (uf >> 1)) {
            const int kf = uf & 1;
            const int ef = kf ? e1 : e0;
            bE[kf] = fexp2(eos[ef] * LOG2E);
            bX[kf] = fexp2(eos[ef + half] * LOG2E);
        }
        int s = 0;
        float teeN1F = teeN1, txeN1F = txeN1;

        float* ringM = sm + RINGF;                    // [2][16][64] floats
        int*   ringS = (int*)(sm + RINGF + 4352);     // [2][2][64]
        const int th = len - 1, tlo = tm + 1;
        const int nbs = th - tlo + 1;
        const int NCH = (nbs > 0) ? ((nbs + 15) >> 4) : 0;
        for (int ph = 0; ph <= NCH; ++ph) {
            const int ci = (wv == 1) ? ph : ph - 1;   // producer = wave1
            if (ci >= 0 && ci < NCH) {
                const int tb = th - (ci << 4);
                int n = tb - tlo + 1; if (n > 16) n = 16;
                float* rM = ringM + (ci & 1) * 1024;
                int*   rS = ringS + (ci & 1) * 128;
                if (wv == 1)
                    nbwd_chunk<false>(st0, st1, bE, bX, s, teeN1F, txeN1F,
                                      teeN0, txeN0, teeN1, txeN1,
                                      tex0, txx0, tex1, txx1,
                                      tb, n, g, lane, rM, rS);
                else
                    nbwd_chunk<true>(st0, st1, bE, bX, s, teeN1F, txeN1F,
                                     teeN0, txeN0, teeN1, txeN1,
                                     tex0, txx0, tex1, txx1,
                                     tb, n, g, lane, rM, rS);
            }
            __syncthreads();
        }
        AST(&NB[g * 4 + 0], bE[0]);
        AST(&NB[g * 4 + 1], bE[1]);
        AST(&NB[g * 4 + 2], bX[0]);
        AST(&NB[g * 4 + 3], bX[1]);
        AST(&NB[512 + g], __int_as_float(s));
    } else {
        // =================== DENOMINATOR (2 waves, proven) ===================
        float* denF  = sm + T * 8 + 16;
        float* denB  = denF + 8;
        int*   denFs = (int*)(denB + 8);
        int*   denBs = denFs + 8;
        const int j  = lane & 7;
        const int jj = ((j & 3) << 1) + (j >> 2);
        if (wv == 0) {
            float Tr[8];
#pragma unroll
            for (int r = 0; r < 8; ++r)
                Tr[r] = fexp2(trans[((j - r) & 7) * S + j] * LOG2E);
            float al = fexp2(bos[j] * LOG2E) * sm[jj];
            int sc = 0;
            int t = 1;
            if (t + 3 <= tm) {
                float c0 = sm[t * 8 + jj];
                float c1 = sm[(t + 1) * 8 + jj];
                float c2 = sm[(t + 2) * 8 + jj];
                float c3 = sm[(t + 3) * 8 + jj];
                pin();
                while (t + 7 <= tm) {
                    float d0 = sm[(t + 4) * 8 + jj];
                    float d1 = sm[(t + 5) * 8 + jj];
                    float d2 = sm[(t + 6) * 8 + jj];
                    float d3 = sm[(t + 7) * 8 + jj];
                    pin();
                    al = denf_step(al, c0, Tr);
                    al = denf_step(al, c1, Tr);
                    al = denf_step(al, c2, Tr);
                    al = denf_step(al, c3, Tr);
                    sc += den_renorm(al);
                    c0 = d0; c1 = d1; c2 = d2; c3 = d3;
                    t += 4;
                }
                al = denf_step(al, c0, Tr);
                al = denf_step(al, c1, Tr);
                al = denf_step(al, c2, Tr);
                al = denf_step(al, c3, Tr);
                sc += den_renorm(al);
                t += 4;
            }
            while (t <= tm) { al = denf_step(al, sm[t * 8 + jj], Tr); ++t; }
            if (lane < 8) { denF[j] = al; denFs[j] = sc; }
        } else {
            float TrB[8];
#pragma unroll
            for (int r = 0; r < 8; ++r)
                TrB[r] = fexp2(trans[j * S + ((j + r) & 7)] * LOG2E);
            float al = fexp2(eos[j] * LOG2E);
            int sc = 0;
            int t = len - 1;
            const int tlo = tm + 1;
            if (t - 3 >= tlo) {
                float c0 = sm[t * 8 + jj];
                float c1 = sm[(t - 1) * 8 + jj];
                float c2 = sm[(t - 2) * 8 + jj];
                float c3 = sm[(t - 3) * 8 + jj];
                pin();
                while (t - 7 >= tlo) {
                    float d0 = sm[(t - 4) * 8 + jj];
                    float d1 = sm[(t - 5) * 8 + jj];
                    float d2 = sm[(t - 6) * 8 + jj];
                    float d3 = sm[(t - 7) * 8 + jj];
                    pin();
                    al = denb_step(al, c0, TrB);
                    al = denb_step(al, c1, TrB);
                    al = denb_step(al, c2, TrB);
                    al = denb_step(al, c3, TrB);
                    sc += den_renorm(al);
                    c0 = d0; c1 = d1; c2 = d2; c3 = d3;
                    t -= 4;
                }
                al = denb_step(al, c0, TrB);
                al = denb_step(al, c1, TrB);
                al = denb_step(al, c2, TrB);
                al = denb_step(al, c3, TrB);
                sc += den_renorm(al);
                t -= 4;
            }
            while (t >= tlo) { al = denb_step(al, sm[t * 8 + jj], TrB); --t; }
            if (lane < 8) { denB[j] = al; denBs[j] = sc; }
        }
        __syncthreads();
        if (wv == 0 && lane < 8) {
            const float a  = fmaxf(denF[j], 1e-37f);
            const float bb = fmaxf(denB[j], 1e-37f);
            float part = flog2(a) + flog2(bb) + (float)(denFs[j] + denBs[j]);
            part = lse2(part, __shfl_xor(part, 1, 64));
            part = lse2(part, __shfl_xor(part, 2, 64));
            part = lse2(part, __shfl_xor(part, 4, 64));
            if (j == 0) AST(&DEN[b], part);
        }
    }

    // ---------------- ticket + winner combine ----------------
    __syncthreads();
    int* wflag = (int*)sm;
    if (tid == 0) {
        __threadfence();
        const int tk = atomicAdd(ticket, 1);
        wflag[0] = (tk == 3 * B - 1) ? 1 : 0;
    }
    __syncthreads();
    if (wflag[0] && tid < 64) {
        __threadfence();
        float acc = 0.0f;
        for (int bb2 = 0; bb2 < B; ++bb2) {
            const float* nf = ws + 16 + (size_t)bb2 * 640;
            const float* nb = ws + 16 + (size_t)B * 640 + (size_t)bb2 * 640;
            float va = 0.0f, vb = 0.0f;
#pragma unroll
            for (int k = 0; k < 4; ++k)
                va = fmaf(ALD(&nf[lane * 4 + k]), ALD(&nb[lane * 4 + k]), va);
#pragma unroll
            for (int k = 0; k < 4; ++k)
                vb = fmaf(ALD(&nf[256 + lane * 4 + k]),
                          ALD(&nb[256 + lane * 4 + k]), vb);
            const int sa = __float_as_int(ALD(&nf[512 + lane]))
                         + __float_as_int(ALD(&nb[512 + lane]));
            const int sb = __float_as_int(ALD(&nf[576 + lane]))
                         + __float_as_int(ALD(&nb[576 + lane]));
            float pa = (va > 0.0f) ? (flog2(va) + (float)sa) : -3.0e38f;
            float pb = (vb > 0.0f) ? (flog2(vb) + (float)sb) : -3.0e38f;
            float part = lse2(pa, pb);
#pragma unroll
            for (int o = 1; o < 64; o <<= 1)
                part = lse2(part, __shfl_xor(part, o, 64));
            if (lane == 0) acc += ALD(&DEN[bb2]) - part;
        }
        if (lane == 0) out[0] = acc * (LN2 / (float)B);
    }
}

extern "C" void kernel_launch(void* const* d_in, const int* in_sizes, int n_in,
                              void* d_out, int out_size, void* d_ws, size_t ws_size,
                              hipStream_t stream)
{
    const float* em      = (const float*)d_in[0];
    const float* trans   = (const float*)d_in[1];
    const float* bos     = (const float*)d_in[2];
    const float* eos     = (const float*)d_in[3];
    const int*   lengths = (const int*)d_in[4];
    const int*   targets = (const int*)d_in[5];
    const int*   tlens   = (const int*)d_in[6];
    float* out = (float*)d_out;
    float* ws  = (float*)d_ws;

    const int B  = in_sizes[4];              // 16
    const int SS = in_sizes[1];              // 64
    int S = 1; while (S * S < SS) ++S;       // 8
    const int T = in_sizes[0] / (B * S);     // 2048
    const int L = in_sizes[5] / B;           // 256

    // num blocks: streams 8*(T+2) + ring (4352 floats EX + 256 ints) floats
    // den blocks: T*8 + 80 floats (smaller). Request the max.
    const size_t shmem = (size_t)(8 * (T + 2) + 4352 + 256) * sizeof(float);

    static bool attr_done = false;
    if (!attr_done) {
        (void)hipFuncSetAttribute((const void*)crf_fused,
                                  hipFuncAttributeMaxDynamicSharedMemorySize,
                                  (int)(96 * 1024));
        attr_done = true;
    }

    (void)hipMemsetAsync(ws, 0, 64, stream); // ticket
    hipLaunchKernelGGL(crf_fused, dim3(3 * B), dim3(128), shmem, stream,
                       em, trans, bos, eos, lengths, targets, tlens,
                       ws, out, B, T, S, L);
}